// Round 12
// baseline (164.475 us; speedup 1.0000x reference)
//
#include <hip/hip_runtime.h>

#define IN_DIM 64
#define OUT_DIM 16
#define NGRID 12      // (NUM+1) + 2*K
#define NB 8          // NUM + K
#define TST 68        // transpose buffer row stride (floats), 2-way banks max
#define ROWS 8        // batch rows per wave

typedef _Float16 half2_t __attribute__((ext_vector_type(2)));
typedef float    fx4     __attribute__((ext_vector_type(4)));

__device__ __forceinline__ half2_t pkrtz(float a, float b) {
    return __builtin_bit_cast(half2_t, __builtin_amdgcn_cvt_pkrtz(a, b));
}

__device__ __forceinline__ float dpp_add16(float v) {
    // sum across each 16-lane DPP row; row_shr accumulates toward higher
    // lanes -> full row sum lands in lane 15 of each row
    int x = __builtin_bit_cast(int, v);
    v += __builtin_bit_cast(float, __builtin_amdgcn_update_dpp(0, x, 0x118, 0xf, 0xf, true)); // row_shr:8
    x = __builtin_bit_cast(int, v);
    v += __builtin_bit_cast(float, __builtin_amdgcn_update_dpp(0, x, 0x114, 0xf, 0xf, true)); // row_shr:4
    x = __builtin_bit_cast(int, v);
    v += __builtin_bit_cast(float, __builtin_amdgcn_update_dpp(0, x, 0x112, 0xf, 0xf, true)); // row_shr:2
    x = __builtin_bit_cast(int, v);
    v += __builtin_bit_cast(float, __builtin_amdgcn_update_dpp(0, x, 0x111, 0xf, 0xf, true)); // row_shr:1
    return v;
}

__global__ __launch_bounds__(256, 3) void kan_fwd_kernel(
    const float* __restrict__ x,      // [B,64]
    const float* __restrict__ grid,   // [64,12]
    const float* __restrict__ coef,   // [64,16,8]
    const float* __restrict__ sbase,  // [64,16]
    const float* __restrict__ ssp,    // [64,16]
    float* __restrict__ out,          // [B,16]
    float* __restrict__ preacts,     // [B,16,64]
    float* __restrict__ postacts,    // [B,16,64]
    float* __restrict__ postspline,  // [B,16,64]
    int batch)
{
    __shared__ float sT[4][OUT_DIM * TST];   // per-wave y transpose buf, 4 x 4.25 KB

    const int tid  = threadIdx.x;
    const int lane = tid & 63;
    const int wave = tid >> 6;
    const int i = lane;

    const long b0 = ((long)blockIdx.x * 4 + wave) * ROWS;
    if (b0 >= batch) return;

    // ---- uniform-grid parameters: t-space needs only g0, 1/h per lane ----
    const float g0 = grid[i * NGRID + 0];
    const float g1 = grid[i * NGRID + 1];
    const float invh = 1.0f / (g1 - g0);

    // ---- coef -> packed f16 registers (64 VGPRs) ----
    half2_t c[OUT_DIM][4];
    {
        const fx4* c4 = reinterpret_cast<const fx4*>(coef + (size_t)i * OUT_DIM * NB);
        #pragma unroll
        for (int o = 0; o < OUT_DIM; ++o) {
            fx4 a = c4[o * 2], bq = c4[o * 2 + 1];
            c[o][0] = pkrtz(a.x,  a.y);
            c[o][1] = pkrtz(a.z,  a.w);
            c[o][2] = pkrtz(bq.x, bq.y);
            c[o][3] = pkrtz(bq.z, bq.w);
        }
    }

    // ---- transposed scales for the post-transpose y2 computation ----
    const int ci = (lane & 15) * 4;   // column (input-dim) base this lane stores
    const int ro = lane >> 4;         // row (output-dim) offset within slice
    float sbt[4][4], spt[4][4];
    #pragma unroll
    for (int sl = 0; sl < 4; ++sl) {
        const int o = sl * 4 + ro;
        #pragma unroll
        for (int k = 0; k < 4; ++k) {
            sbt[sl][k] = sbase[(ci + k) * OUT_DIM + o];
            spt[sl][k] = ssp  [(ci + k) * OUT_DIM + o];
        }
    }

    float* sTw = sT[wave];
    float xi_cur = x[b0 * IN_DIM + i];

    #pragma unroll 1
    for (int r = 0; r < ROWS; ++r) {
        const long b = b0 + r;
        if (b >= batch) break;
        float xi_next = 0.0f;
        if (r + 1 < ROWS && b + 1 < batch) xi_next = x[(b + 1) * IN_DIM + i];
        const float xi = xi_cur;

        // ---- spline basis in t-space (uniform knots) ----
        const float t = (xi - g0) * invh;
        float d[NGRID];
        #pragma unroll
        for (int j = 0; j < NGRID; ++j) d[j] = t - (float)j;

        float Bv[11];
        #pragma unroll
        for (int j = 0; j < 11; ++j)
            Bv[j] = (d[j] >= 0.0f && d[j + 1] < 0.0f) ? 1.0f : 0.0f;

        #pragma unroll
        for (int j = 0; j < 10; ++j)
            Bv[j] = d[j] * Bv[j] - d[j + 2] * Bv[j + 1];                       // p=1, /1
        #pragma unroll
        for (int j = 0; j < 9; ++j)
            Bv[j] = (d[j] * Bv[j] - d[j + 3] * Bv[j + 1]) * 0.5f;              // p=2
        #pragma unroll
        for (int j = 0; j < 8; ++j)
            Bv[j] = (d[j] * Bv[j] - d[j + 4] * Bv[j + 1]) * (1.0f / 3.0f);     // p=3

        // pack basis to f16 pairs
        half2_t bh[4];
        #pragma unroll
        for (int q = 0; q < 4; ++q)
            bh[q] = pkrtz(Bv[2 * q], Bv[2 * q + 1]);

        // ---- spline dot via v_dot2_f32_f16, write y to transpose buffer ----
        #pragma unroll
        for (int o = 0; o < OUT_DIM; ++o) {
            float y = __builtin_amdgcn_fdot2(c[o][0], bh[0],
                      __builtin_amdgcn_fdot2(c[o][1], bh[1],
                      __builtin_amdgcn_fdot2(c[o][2], bh[2],
                      __builtin_amdgcn_fdot2(c[o][3], bh[3], 0.0f, false),
                      false), false), false);
            sTw[o * TST + i] = y;
        }

        // ---- gather this lane's 4 input dims: x and silu(x) ----
        const float base = xi / (1.0f + __expf(-xi));
        fx4 xq, bq;
        xq.x = __shfl(xi, ci + 0, 64);  bq.x = __shfl(base, ci + 0, 64);
        xq.y = __shfl(xi, ci + 1, 64);  bq.y = __shfl(base, ci + 1, 64);
        xq.z = __shfl(xi, ci + 2, 64);  bq.z = __shfl(base, ci + 2, 64);
        xq.w = __shfl(xi, ci + 3, 64);  bq.w = __shfl(base, ci + 3, 64);

        const size_t rowoff = (size_t)b * (OUT_DIM * IN_DIM);
        float ps0, ps1, ps2, ps3;

        #pragma unroll
        for (int sl = 0; sl < 4; ++sl) {
            const int row = sl * 4 + ro;
            fx4 yv = *reinterpret_cast<const fx4*>(&sTw[row * TST + ci]);
            fx4 y2;
            y2.x = __builtin_fmaf(sbt[sl][0], bq.x, spt[sl][0] * yv.x);
            y2.y = __builtin_fmaf(sbt[sl][1], bq.y, spt[sl][1] * yv.y);
            y2.z = __builtin_fmaf(sbt[sl][2], bq.z, spt[sl][2] * yv.z);
            y2.w = __builtin_fmaf(sbt[sl][3], bq.w, spt[sl][3] * yv.w);

            const size_t goff = rowoff + (size_t)sl * 256 + 4 * lane;
            __builtin_nontemporal_store(yv, reinterpret_cast<fx4*>(&postspline[goff]));
            __builtin_nontemporal_store(y2, reinterpret_cast<fx4*>(&postacts[goff]));
            __builtin_nontemporal_store(xq, reinterpret_cast<fx4*>(&preacts[goff]));

            const float ps = (y2.x + y2.y) + (y2.z + y2.w);
            if (sl == 0) ps0 = ps; else if (sl == 1) ps1 = ps;
            else if (sl == 2) ps2 = ps; else ps3 = ps;
        }

        // ---- out[b, o]: DPP reduction; row sum is in lane 15 of each row ----
        ps0 = dpp_add16(ps0);
        ps1 = dpp_add16(ps1);
        ps2 = dpp_add16(ps2);
        ps3 = dpp_add16(ps3);
        if ((lane & 15) == 15) {
            float* ob = out + (size_t)b * OUT_DIM;
            ob[0  + ro] = ps0;
            ob[4  + ro] = ps1;
            ob[8  + ro] = ps2;
            ob[12 + ro] = ps3;
        }

        xi_cur = xi_next;
    }
}

extern "C" void kernel_launch(void* const* d_in, const int* in_sizes, int n_in,
                              void* d_out, int out_size, void* d_ws, size_t ws_size,
                              hipStream_t stream) {
    const float* x     = (const float*)d_in[0];
    const float* grid  = (const float*)d_in[1];
    const float* coef  = (const float*)d_in[2];
    const float* sbase = (const float*)d_in[3];
    const float* ssp   = (const float*)d_in[4];

    const int batch = in_sizes[0] / IN_DIM;

    float* out = (float*)d_out;
    float* preacts    = out + (size_t)batch * OUT_DIM;
    float* postacts   = preacts  + (size_t)batch * OUT_DIM * IN_DIM;
    float* postspline = postacts + (size_t)batch * OUT_DIM * IN_DIM;

    const int rows_per_block = 4 * ROWS;     // 4 waves x 8 rows
    const int nblocks = (batch + rows_per_block - 1) / rows_per_block;
    kan_fwd_kernel<<<nblocks, 256, 0, stream>>>(
        x, grid, coef, sbase, ssp, out, preacts, postacts, postspline, batch);
}